// Round 7
// baseline (650.626 us; speedup 1.0000x reference)
//
#include <hip/hip_runtime.h>

#define TOKENS 16384
#define DDIM 4096
#define RANK 32
#define TOPK 8
#define DSUB 32
#define TILE_T 256   // tokens per block; lane owns 4 (lane, +64, +128, +192)
#define NTOKP 257    // padded token slots -> staging writes <=2 lanes/bank-slot

// ---------------- K1: y_part[db][t][r] = sum_{d in chunk} x[t][d]*A[r][d]
// grid (TOKENS/256, ndb), block 256 (4 waves; wave w -> ranks w*8..w*8+7).
// BOTH operands come from LDS: x per-lane (token-major, padded), A via
// uniform-address ds_read_b128 broadcasts (conflict-free). DS is in-order ->
// partial lgkmcnt waits pipeline reads under FMAs; no lgkmcnt(0) drains
// (the SMEM/s_load wall of r2-r6), no per-lane A arrays (the r6 scratch bug).
__global__ __launch_bounds__(256, 4) void k1_proj(const float* __restrict__ x,
                                                  const float* __restrict__ A,
                                                  float* __restrict__ y_part,
                                                  int dblk, int nsub) {
  const int tid = threadIdx.x;
  const int lane = tid & 63;
  const int wid = __builtin_amdgcn_readfirstlane(tid >> 6);
  const int r0 = wid * 8;
  const int t0 = blockIdx.x * TILE_T;
  const int db = blockIdx.y;

  __shared__ float xs[8 * NTOKP * 4];  // [dim-quad][token(257)][4] = 32.9 KB
  __shared__ float as_[RANK * DSUB];   // [rank][dim] = 4 KB

  float acc[4][8];
#pragma unroll
  for (int ti = 0; ti < 4; ++ti)
#pragma unroll
    for (int r = 0; r < 8; ++r) acc[ti][r] = 0.f;

  const int li = tid & 7;   // dim-quad for x staging
  const int th = tid >> 3;  // 0..31 token base
  const int ar = tid >> 3;  // rank for A staging
  const int ak = tid & 7;   // dim-quad for A staging

  for (int sub = 0; sub < nsub; ++sub) {
    const int d0 = db * dblk + sub * DSUB;

    // stage A: 32 ranks x 32 dims, one float4/thread (slots all distinct)
    {
      const float4 v = *reinterpret_cast<const float4*>(
          &A[(size_t)ar * DDIM + d0 + ak * 4]);
      *reinterpret_cast<float4*>(&as_[ar * DSUB + ak * 4]) = v;
    }
    // stage x: 256 tokens x 32 dims (32 KB); 8 threads/token read 128B rows
#pragma unroll
    for (int jj = 0; jj < 8; ++jj) {
      const int t = th + 32 * jj;
      const float4 v = *reinterpret_cast<const float4*>(
          &x[(size_t)(t0 + t) * DDIM + d0 + li * 4]);
      *reinterpret_cast<float4*>(&xs[(li * NTOKP + t) * 4]) = v;
    }
    __syncthreads();

#pragma unroll
    for (int g = 0; g < 4; ++g) {  // 8-dim groups
      // x fragment: 4 tokens x 8 dims = 8 ds_read_b128 (contiguous, free)
      float xv[4][8];
#pragma unroll
      for (int q = 0; q < 2; ++q)
#pragma unroll
        for (int ti = 0; ti < 4; ++ti) {
          const float4 v = *reinterpret_cast<const float4*>(
              &xs[((2 * g + q) * NTOKP + lane + ti * 64) * 4]);
          xv[ti][q * 4 + 0] = v.x; xv[ti][q * 4 + 1] = v.y;
          xv[ti][q * 4 + 2] = v.z; xv[ti][q * 4 + 3] = v.w;
        }

      // per rank: 2 uniform-broadcast b128 A-reads, consumed immediately
      // (8 transient floats -> registers, not scratch); 32 FMAs cover them
#pragma unroll
      for (int r = 0; r < 8; ++r) {
        const float4 a0 = *reinterpret_cast<const float4*>(
            &as_[(r0 + r) * DSUB + g * 8]);
        const float4 a1 = *reinterpret_cast<const float4*>(
            &as_[(r0 + r) * DSUB + g * 8 + 4]);
        float s0 = 0.f, s1 = 0.f, s2 = 0.f, s3 = 0.f;
        s0 = fmaf(xv[0][0], a0.x, s0); s1 = fmaf(xv[1][0], a0.x, s1);
        s2 = fmaf(xv[2][0], a0.x, s2); s3 = fmaf(xv[3][0], a0.x, s3);
        s0 = fmaf(xv[0][1], a0.y, s0); s1 = fmaf(xv[1][1], a0.y, s1);
        s2 = fmaf(xv[2][1], a0.y, s2); s3 = fmaf(xv[3][1], a0.y, s3);
        s0 = fmaf(xv[0][2], a0.z, s0); s1 = fmaf(xv[1][2], a0.z, s1);
        s2 = fmaf(xv[2][2], a0.z, s2); s3 = fmaf(xv[3][2], a0.z, s3);
        s0 = fmaf(xv[0][3], a0.w, s0); s1 = fmaf(xv[1][3], a0.w, s1);
        s2 = fmaf(xv[2][3], a0.w, s2); s3 = fmaf(xv[3][3], a0.w, s3);
        s0 = fmaf(xv[0][4], a1.x, s0); s1 = fmaf(xv[1][4], a1.x, s1);
        s2 = fmaf(xv[2][4], a1.x, s2); s3 = fmaf(xv[3][4], a1.x, s3);
        s0 = fmaf(xv[0][5], a1.y, s0); s1 = fmaf(xv[1][5], a1.y, s1);
        s2 = fmaf(xv[2][5], a1.y, s2); s3 = fmaf(xv[3][5], a1.y, s3);
        s0 = fmaf(xv[0][6], a1.z, s0); s1 = fmaf(xv[1][6], a1.z, s1);
        s2 = fmaf(xv[2][6], a1.z, s2); s3 = fmaf(xv[3][6], a1.z, s3);
        s0 = fmaf(xv[0][7], a1.w, s0); s1 = fmaf(xv[1][7], a1.w, s1);
        s2 = fmaf(xv[2][7], a1.w, s2); s3 = fmaf(xv[3][7], a1.w, s3);
        acc[0][r] += s0;  // two-level fp32 accumulation (tight vs np ref)
        acc[1][r] += s1;
        acc[2][r] += s2;
        acc[3][r] += s3;
      }
    }
    __syncthreads();
  }

#pragma unroll
  for (int ti = 0; ti < 4; ++ti) {
    float* yp =
        &y_part[((size_t)db * TOKENS + t0 + lane + ti * 64) * RANK + r0];
    float4 o0 = {acc[ti][0], acc[ti][1], acc[ti][2], acc[ti][3]};
    float4 o1 = {acc[ti][4], acc[ti][5], acc[ti][6], acc[ti][7]};
    reinterpret_cast<float4*>(yp)[0] = o0;
    reinterpret_cast<float4*>(yp)[1] = o1;
  }
}

// ---------------- K2: reduce partials, bias, |.| top-8, w = 2*y*mask -------
__global__ __launch_bounds__(64) void k2_topk(const float* __restrict__ y_part,
                                              const float* __restrict__ dbias,
                                              float* __restrict__ w, int ndb) {
  const int t = blockIdx.x * 64 + threadIdx.x;
  float yv[RANK];
#pragma unroll
  for (int r = 0; r < RANK; ++r) yv[r] = 0.f;
  for (int c = 0; c < ndb; ++c) {
    const float* yp = &y_part[((size_t)c * TOKENS + t) * RANK];
#pragma unroll
    for (int q = 0; q < RANK / 4; ++q) {
      const float4 v = reinterpret_cast<const float4*>(yp)[q];
      yv[q * 4 + 0] += v.x; yv[q * 4 + 1] += v.y;
      yv[q * 4 + 2] += v.z; yv[q * 4 + 3] += v.w;
    }
  }

  float ab[RANK];
#pragma unroll
  for (int r = 0; r < RANK; ++r) ab[r] = fabsf(yv[r] + dbias[r]);

  unsigned mask = 0;
#pragma unroll
  for (int k = 0; k < TOPK; ++k) {
    float best = -1.f;
    int bi = 0;
#pragma unroll
    for (int r = 0; r < RANK; ++r) {
      // strict > keeps lowest index on ties == jax.lax.top_k stability
      const bool sel = (((mask >> r) & 1u) == 0u) && (ab[r] > best);
      best = sel ? ab[r] : best;
      bi = sel ? r : bi;
    }
    mask |= 1u << bi;
  }

  float* wp = &w[(size_t)t * RANK];
#pragma unroll
  for (int q = 0; q < RANK / 4; ++q) {
    float4 o;
    o.x = ((mask >> (q * 4 + 0)) & 1u) ? 2.0f * yv[q * 4 + 0] : 0.f;
    o.y = ((mask >> (q * 4 + 1)) & 1u) ? 2.0f * yv[q * 4 + 1] : 0.f;
    o.z = ((mask >> (q * 4 + 2)) & 1u) ? 2.0f * yv[q * 4 + 2] : 0.f;
    o.w = ((mask >> (q * 4 + 3)) & 1u) ? 2.0f * yv[q * 4 + 3] : 0.f;
    reinterpret_cast<float4*>(wp)[q] = o;
  }
}

// ---------------- K3: out[t][o] = sum_r w[t][r] * B[o][r] ----------------
// grid (DDIM/512, TOKENS/64), block 256. w rows staged in LDS; per-token
// reads are uniform-broadcast ds_read_b128 (in-order lgkmcnt -> pipelines).
#define K3_TOK 64

__global__ __launch_bounds__(256) void k3_out(const float* __restrict__ w,
                                              const float* __restrict__ B,
                                              float* __restrict__ out) {
  const int tid = threadIdx.x;
  const int c0 = blockIdx.x * 512 + tid * 2;
  const int tbase = blockIdx.y * K3_TOK;

  __shared__ float wl[K3_TOK * RANK];  // 8 KB

  float b0[RANK], b1[RANK];
#pragma unroll
  for (int q = 0; q < RANK / 4; ++q) {
    const float4 v0 = reinterpret_cast<const float4*>(&B[(size_t)c0 * RANK])[q];
    const float4 v1 =
        reinterpret_cast<const float4*>(&B[(size_t)(c0 + 1) * RANK])[q];
    b0[q * 4 + 0] = v0.x; b0[q * 4 + 1] = v0.y;
    b0[q * 4 + 2] = v0.z; b0[q * 4 + 3] = v0.w;
    b1[q * 4 + 0] = v1.x; b1[q * 4 + 1] = v1.y;
    b1[q * 4 + 2] = v1.z; b1[q * 4 + 3] = v1.w;
  }

  // stage w[tbase..tbase+64)[0..32): 2048 contiguous floats, coalesced
  const float4* wg = reinterpret_cast<const float4*>(&w[(size_t)tbase * RANK]);
#pragma unroll
  for (int jj = 0; jj < 2; ++jj) {
    const int slot = tid + 256 * jj;  // 512 float4 slots
    reinterpret_cast<float4*>(wl)[slot] = wg[slot];
  }
  __syncthreads();

#pragma unroll 4
  for (int tt = 0; tt < K3_TOK; ++tt) {
    float s0 = 0.f, s1 = 0.f;
#pragma unroll
    for (int q = 0; q < RANK / 4; ++q) {
      const float4 wv = reinterpret_cast<const float4*>(wl)[tt * 8 + q];
      s0 = fmaf(wv.x, b0[q * 4 + 0], s0); s1 = fmaf(wv.x, b1[q * 4 + 0], s1);
      s0 = fmaf(wv.y, b0[q * 4 + 1], s0); s1 = fmaf(wv.y, b1[q * 4 + 1], s1);
      s0 = fmaf(wv.z, b0[q * 4 + 2], s0); s1 = fmaf(wv.z, b1[q * 4 + 2], s1);
      s0 = fmaf(wv.w, b0[q * 4 + 3], s0); s1 = fmaf(wv.w, b1[q * 4 + 3], s1);
    }
    float2 o;
    o.x = s0;
    o.y = s1;
    *reinterpret_cast<float2*>(&out[(size_t)(tbase + tt) * DDIM + c0]) = o;
  }
}

extern "C" void kernel_launch(void* const* d_in, const int* in_sizes, int n_in,
                              void* d_out, int out_size, void* d_ws,
                              size_t ws_size, hipStream_t stream) {
  const float* x = (const float*)d_in[0];
  const float* A = (const float*)d_in[1];
  const float* B = (const float*)d_in[2];
  const float* dbias = (const float*)d_in[3];
  float* out = (float*)d_out;

  const size_t plane = (size_t)TOKENS * RANK;  // 512K floats = 2 MB
  int ndb = 16;  // 1024 k1 blocks = 4/CU at 37 KB LDS
  while (ndb > 1 && ws_size < (size_t)(ndb + 1) * plane * sizeof(float))
    ndb >>= 1;
  const int dblk = DDIM / ndb;
  const int nsub = dblk / DSUB;

  float* y_part = (float*)d_ws;             // ndb planes
  float* w = y_part + (size_t)ndb * plane;  // 1 plane

  k1_proj<<<dim3(TOKENS / TILE_T, ndb), 256, 0, stream>>>(x, A, y_part, dblk,
                                                          nsub);
  k2_topk<<<TOKENS / 64, 64, 0, stream>>>(y_part, dbias, w, ndb);
  k3_out<<<dim3(DDIM / 512, TOKENS / K3_TOK), 256, 0, stream>>>(w, B, out);
}

// Round 8
// 246.122 us; speedup vs baseline: 2.6435x; 2.6435x over previous
//
#include <hip/hip_runtime.h>

#define TOKENS 16384
#define DDIM 4096
#define RANK 32
#define TOPK 8
#define DSUB 32
#define TILE_T 256   // tokens per block; lane owns 4 (lane, +64, +128, +192)
#define NTOKP 257    // padded token slots -> staging writes <=2 lanes/bank-slot

// ---------------- K1: y_part[db][t][r] = sum_{d in chunk} x[t][d]*A[r][d]
// grid (TOKENS/256, ndb), block 256 (4 waves; wave w -> ranks w*8..w*8+7).
// BOTH operands come from LDS: x per-lane (token-major, padded), A via
// uniform-address ds_read_b128 broadcasts (conflict-free). DS is in-order ->
// partial lgkmcnt waits pipeline reads under FMAs; no lgkmcnt(0) drains.
// NOTE: no min-waves launch_bounds arg — (256,4) capped VGPR at 64 and
// spilled the 90-reg live set to scratch (r6/r7: 0.3-2 GB scratch traffic).
__global__ __launch_bounds__(256) void k1_proj(const float* __restrict__ x,
                                               const float* __restrict__ A,
                                               float* __restrict__ y_part,
                                               int dblk, int nsub) {
  const int tid = threadIdx.x;
  const int lane = tid & 63;
  const int wid = __builtin_amdgcn_readfirstlane(tid >> 6);
  const int r0 = wid * 8;
  const int t0 = blockIdx.x * TILE_T;
  const int db = blockIdx.y;

  __shared__ float xs[8 * NTOKP * 4];  // [dim-quad][token(257)][4] = 32.9 KB
  __shared__ float as_[RANK * DSUB];   // [rank][dim] = 4 KB

  float acc[4][8];
#pragma unroll
  for (int ti = 0; ti < 4; ++ti)
#pragma unroll
    for (int r = 0; r < 8; ++r) acc[ti][r] = 0.f;

  const int li = tid & 7;   // dim-quad for x staging
  const int th = tid >> 3;  // 0..31 token base
  const int ar = tid >> 3;  // rank for A staging
  const int ak = tid & 7;   // dim-quad for A staging

  for (int sub = 0; sub < nsub; ++sub) {
    const int d0 = db * dblk + sub * DSUB;

    // stage A: 32 ranks x 32 dims, one float4/thread (slots all distinct)
    {
      const float4 v = *reinterpret_cast<const float4*>(
          &A[(size_t)ar * DDIM + d0 + ak * 4]);
      *reinterpret_cast<float4*>(&as_[ar * DSUB + ak * 4]) = v;
    }
    // stage x: 256 tokens x 32 dims (32 KB); 8 threads/token read 128B rows
#pragma unroll
    for (int jj = 0; jj < 8; ++jj) {
      const int t = th + 32 * jj;
      const float4 v = *reinterpret_cast<const float4*>(
          &x[(size_t)(t0 + t) * DDIM + d0 + li * 4]);
      *reinterpret_cast<float4*>(&xs[(li * NTOKP + t) * 4]) = v;
    }
    __syncthreads();

#pragma unroll
    for (int g = 0; g < 4; ++g) {  // 8-dim groups
      // x fragment: 4 tokens x 8 dims = 8 ds_read_b128 (2-way banked = free)
      float xv[4][8];
#pragma unroll
      for (int q = 0; q < 2; ++q)
#pragma unroll
        for (int ti = 0; ti < 4; ++ti) {
          const float4 v = *reinterpret_cast<const float4*>(
              &xs[((2 * g + q) * NTOKP + lane + ti * 64) * 4]);
          xv[ti][q * 4 + 0] = v.x; xv[ti][q * 4 + 1] = v.y;
          xv[ti][q * 4 + 2] = v.z; xv[ti][q * 4 + 3] = v.w;
        }

      // per rank: 2 uniform-broadcast b128 A-reads, consumed immediately
      // (transient 8 floats -> registers); 32 FMAs cover them
#pragma unroll
      for (int r = 0; r < 8; ++r) {
        const float4 a0 = *reinterpret_cast<const float4*>(
            &as_[(r0 + r) * DSUB + g * 8]);
        const float4 a1 = *reinterpret_cast<const float4*>(
            &as_[(r0 + r) * DSUB + g * 8 + 4]);
        float s0 = 0.f, s1 = 0.f, s2 = 0.f, s3 = 0.f;
        s0 = fmaf(xv[0][0], a0.x, s0); s1 = fmaf(xv[1][0], a0.x, s1);
        s2 = fmaf(xv[2][0], a0.x, s2); s3 = fmaf(xv[3][0], a0.x, s3);
        s0 = fmaf(xv[0][1], a0.y, s0); s1 = fmaf(xv[1][1], a0.y, s1);
        s2 = fmaf(xv[2][1], a0.y, s2); s3 = fmaf(xv[3][1], a0.y, s3);
        s0 = fmaf(xv[0][2], a0.z, s0); s1 = fmaf(xv[1][2], a0.z, s1);
        s2 = fmaf(xv[2][2], a0.z, s2); s3 = fmaf(xv[3][2], a0.z, s3);
        s0 = fmaf(xv[0][3], a0.w, s0); s1 = fmaf(xv[1][3], a0.w, s1);
        s2 = fmaf(xv[2][3], a0.w, s2); s3 = fmaf(xv[3][3], a0.w, s3);
        s0 = fmaf(xv[0][4], a1.x, s0); s1 = fmaf(xv[1][4], a1.x, s1);
        s2 = fmaf(xv[2][4], a1.x, s2); s3 = fmaf(xv[3][4], a1.x, s3);
        s0 = fmaf(xv[0][5], a1.y, s0); s1 = fmaf(xv[1][5], a1.y, s1);
        s2 = fmaf(xv[2][5], a1.y, s2); s3 = fmaf(xv[3][5], a1.y, s3);
        s0 = fmaf(xv[0][6], a1.z, s0); s1 = fmaf(xv[1][6], a1.z, s1);
        s2 = fmaf(xv[2][6], a1.z, s2); s3 = fmaf(xv[3][6], a1.z, s3);
        s0 = fmaf(xv[0][7], a1.w, s0); s1 = fmaf(xv[1][7], a1.w, s1);
        s2 = fmaf(xv[2][7], a1.w, s2); s3 = fmaf(xv[3][7], a1.w, s3);
        acc[0][r] += s0;  // two-level fp32 accumulation (tight vs np ref)
        acc[1][r] += s1;
        acc[2][r] += s2;
        acc[3][r] += s3;
      }
    }
    __syncthreads();
  }

#pragma unroll
  for (int ti = 0; ti < 4; ++ti) {
    float* yp =
        &y_part[((size_t)db * TOKENS + t0 + lane + ti * 64) * RANK + r0];
    float4 o0 = {acc[ti][0], acc[ti][1], acc[ti][2], acc[ti][3]};
    float4 o1 = {acc[ti][4], acc[ti][5], acc[ti][6], acc[ti][7]};
    reinterpret_cast<float4*>(yp)[0] = o0;
    reinterpret_cast<float4*>(yp)[1] = o1;
  }
}

// ---------------- K2: reduce partials, bias, |.| top-8, w = 2*y*mask -------
__global__ __launch_bounds__(64) void k2_topk(const float* __restrict__ y_part,
                                              const float* __restrict__ dbias,
                                              float* __restrict__ w, int ndb) {
  const int t = blockIdx.x * 64 + threadIdx.x;
  float yv[RANK];
#pragma unroll
  for (int r = 0; r < RANK; ++r) yv[r] = 0.f;
  for (int c = 0; c < ndb; ++c) {
    const float* yp = &y_part[((size_t)c * TOKENS + t) * RANK];
#pragma unroll
    for (int q = 0; q < RANK / 4; ++q) {
      const float4 v = reinterpret_cast<const float4*>(yp)[q];
      yv[q * 4 + 0] += v.x; yv[q * 4 + 1] += v.y;
      yv[q * 4 + 2] += v.z; yv[q * 4 + 3] += v.w;
    }
  }

  float ab[RANK];
#pragma unroll
  for (int r = 0; r < RANK; ++r) ab[r] = fabsf(yv[r] + dbias[r]);

  unsigned mask = 0;
#pragma unroll
  for (int k = 0; k < TOPK; ++k) {
    float best = -1.f;
    int bi = 0;
#pragma unroll
    for (int r = 0; r < RANK; ++r) {
      // strict > keeps lowest index on ties == jax.lax.top_k stability
      const bool sel = (((mask >> r) & 1u) == 0u) && (ab[r] > best);
      best = sel ? ab[r] : best;
      bi = sel ? r : bi;
    }
    mask |= 1u << bi;
  }

  float* wp = &w[(size_t)t * RANK];
#pragma unroll
  for (int q = 0; q < RANK / 4; ++q) {
    float4 o;
    o.x = ((mask >> (q * 4 + 0)) & 1u) ? 2.0f * yv[q * 4 + 0] : 0.f;
    o.y = ((mask >> (q * 4 + 1)) & 1u) ? 2.0f * yv[q * 4 + 1] : 0.f;
    o.z = ((mask >> (q * 4 + 2)) & 1u) ? 2.0f * yv[q * 4 + 2] : 0.f;
    o.w = ((mask >> (q * 4 + 3)) & 1u) ? 2.0f * yv[q * 4 + 3] : 0.f;
    reinterpret_cast<float4*>(wp)[q] = o;
  }
}

// ---------------- K3: out[t][o] = sum_r w[t][r] * B[o][r] ----------------
// grid (DDIM/512, TOKENS/64), block 256. w rows staged in LDS; per-token
// reads are uniform-broadcast ds_read_b128 (in-order lgkmcnt -> pipelines).
#define K3_TOK 64

__global__ __launch_bounds__(256) void k3_out(const float* __restrict__ w,
                                              const float* __restrict__ B,
                                              float* __restrict__ out) {
  const int tid = threadIdx.x;
  const int c0 = blockIdx.x * 512 + tid * 2;
  const int tbase = blockIdx.y * K3_TOK;

  __shared__ float wl[K3_TOK * RANK];  // 8 KB

  float b0[RANK], b1[RANK];
#pragma unroll
  for (int q = 0; q < RANK / 4; ++q) {
    const float4 v0 = reinterpret_cast<const float4*>(&B[(size_t)c0 * RANK])[q];
    const float4 v1 =
        reinterpret_cast<const float4*>(&B[(size_t)(c0 + 1) * RANK])[q];
    b0[q * 4 + 0] = v0.x; b0[q * 4 + 1] = v0.y;
    b0[q * 4 + 2] = v0.z; b0[q * 4 + 3] = v0.w;
    b1[q * 4 + 0] = v1.x; b1[q * 4 + 1] = v1.y;
    b1[q * 4 + 2] = v1.z; b1[q * 4 + 3] = v1.w;
  }

  // stage w[tbase..tbase+64)[0..32): 2048 contiguous floats, coalesced
  const float4* wg = reinterpret_cast<const float4*>(&w[(size_t)tbase * RANK]);
#pragma unroll
  for (int jj = 0; jj < 2; ++jj) {
    const int slot = tid + 256 * jj;  // 512 float4 slots
    reinterpret_cast<float4*>(wl)[slot] = wg[slot];
  }
  __syncthreads();

#pragma unroll 4
  for (int tt = 0; tt < K3_TOK; ++tt) {
    float s0 = 0.f, s1 = 0.f;
#pragma unroll
    for (int q = 0; q < RANK / 4; ++q) {
      const float4 wv = reinterpret_cast<const float4*>(wl)[tt * 8 + q];
      s0 = fmaf(wv.x, b0[q * 4 + 0], s0); s1 = fmaf(wv.x, b1[q * 4 + 0], s1);
      s0 = fmaf(wv.y, b0[q * 4 + 1], s0); s1 = fmaf(wv.y, b1[q * 4 + 1], s1);
      s0 = fmaf(wv.z, b0[q * 4 + 2], s0); s1 = fmaf(wv.z, b1[q * 4 + 2], s1);
      s0 = fmaf(wv.w, b0[q * 4 + 3], s0); s1 = fmaf(wv.w, b1[q * 4 + 3], s1);
    }
    float2 o;
    o.x = s0;
    o.y = s1;
    *reinterpret_cast<float2*>(&out[(size_t)(tbase + tt) * DDIM + c0]) = o;
  }
}

extern "C" void kernel_launch(void* const* d_in, const int* in_sizes, int n_in,
                              void* d_out, int out_size, void* d_ws,
                              size_t ws_size, hipStream_t stream) {
  const float* x = (const float*)d_in[0];
  const float* A = (const float*)d_in[1];
  const float* B = (const float*)d_in[2];
  const float* dbias = (const float*)d_in[3];
  float* out = (float*)d_out;

  const size_t plane = (size_t)TOKENS * RANK;  // 512K floats = 2 MB
  int ndb = 16;  // 1024 k1 blocks = 4/CU at 37 KB LDS
  while (ndb > 1 && ws_size < (size_t)(ndb + 1) * plane * sizeof(float))
    ndb >>= 1;
  const int dblk = DDIM / ndb;
  const int nsub = dblk / DSUB;

  float* y_part = (float*)d_ws;             // ndb planes
  float* w = y_part + (size_t)ndb * plane;  // 1 plane

  k1_proj<<<dim3(TOKENS / TILE_T, ndb), 256, 0, stream>>>(x, A, y_part, dblk,
                                                          nsub);
  k2_topk<<<TOKENS / 64, 64, 0, stream>>>(y_part, dbias, w, ndb);
  k3_out<<<dim3(DDIM / 512, TOKENS / K3_TOK), 256, 0, stream>>>(w, B, out);
}